// Round 1
// baseline (707.322 us; speedup 1.0000x reference)
//
#include <hip/hip_runtime.h>

#define Bdim 64
#define Sdim 50
#define Tdim 200
#define Ddim 128
#define IN2d 128
#define Hdim 64
#define NBS  (Bdim * Sdim)   // 3200
#define NEGV (-1e10f)

__device__ __forceinline__ float ftanh(float x) {
    // tanh(x) = 1 - 2/(exp(2x)+1); exp overflow -> inf -> rcp -> 0 -> 1 (correct tail)
    float e = __expf(2.0f * x);
    float r = __builtin_amdgcn_rcpf(e + 1.0f);
    return 1.0f - 2.0f * r;
}

// ---- prep kernel 1: W1 [H,D] -> W1T [D,H] so the main kernel's scalar loads are contiguous
__global__ void transpose_w1(const float* __restrict__ W1, float* __restrict__ W1T) {
    int idx = blockIdx.x * blockDim.x + threadIdx.x;   // 0..8191
    if (idx < Hdim * Ddim) {
        int h = idx >> 7, d = idx & 127;
        W1T[d * Hdim + h] = W1[idx];
    }
}

// ---- prep kernel 2: w2h[bs][h] = z[bs,:] . W2_w[h,:] + W2_b[h]
__global__ void compute_w2h(const float* __restrict__ z, const float* __restrict__ W2w,
                            const float* __restrict__ W2b, float* __restrict__ w2h) {
    __shared__ float w2s[Hdim * 129];   // +1 pad: lane-h reads are 2-way (free)
    __shared__ float zred[256];
    const int tid = threadIdx.x;
    for (int i = tid; i < Hdim * IN2d; i += 256) {
        int h = i >> 7, d = i & 127;
        w2s[h * 129 + d] = W2w[i];
    }
    __syncthreads();
    const int h = tid & 63, q = tid >> 6;
    for (int i = 0; i < NBS / 64; ++i) {       // 50 bs per block
        const int bs = blockIdx.x * (NBS / 64) + i;
        const float* zp = z + bs * IN2d;       // uniform -> s_load broadcast
        float a = 0.f;
        #pragma unroll
        for (int dk = 0; dk < 32; ++dk) {
            int d = q * 32 + dk;
            a = fmaf(zp[d], w2s[h * 129 + d], a);
        }
        zred[tid] = a;
        __syncthreads();
        if (tid < Hdim)
            w2h[bs * Hdim + tid] =
                zred[tid] + zred[64 + tid] + zred[128 + tid] + zred[192 + tid] + W2b[tid];
        __syncthreads();
    }
}

// ---- main kernel: one block per (b,s)
__global__ __launch_bounds__(256) void attn_main(
    const float* __restrict__ X, const int* __restrict__ mask,
    const float* __restrict__ Vw, const float* __restrict__ Vb,
    const float* __restrict__ W1T, const float* __restrict__ w2h_g,
    float* __restrict__ out)
{
    // LDS: 64*201*4 = 51456 + 800 + 256 + 32 = 52544 B -> 3 blocks/CU
    __shared__ float xs[64 * 201];     // [dd][t], t-stride 201 (bank offset 9/dd row)
    __shared__ float att[Tdim];
    __shared__ float w2h_s[Hdim];
    __shared__ float red[8];

    const int tid = threadIdx.x;
    const int bs  = blockIdx.x;
    const float* __restrict__ Xb = X + (size_t)bs * (Tdim * Ddim);

    if (tid < Hdim) w2h_s[tid] = w2h_g[bs * Hdim + tid];

    const int t = tid;                  // lane's T row (valid if < 200)
    float acc[Hdim];
    #pragma unroll
    for (int h = 0; h < Hdim; ++h) acc[h] = 0.f;

    // ---- pass 1: w1h accumulation over two 64-wide d-chunks
    for (int c = 0; c < 2; ++c) {
        const int d0 = c * 64;
        if (c) __syncthreads();         // chunk-0 readers done before overwrite
        // stage X[:, d0:d0+64] transposed into LDS (3200 float4 loads, coalesced)
        for (int j = tid; j < Tdim * 16; j += 256) {
            int tt = j >> 4, dq = j & 15;
            const float4 v = *(const float4*)(Xb + tt * Ddim + d0 + dq * 4);
            int base = (dq * 4) * 201 + tt;
            xs[base]       = v.x;
            xs[base + 201] = v.y;
            xs[base + 402] = v.z;
            xs[base + 603] = v.w;
        }
        __syncthreads();
        if (t < Tdim) {
            #pragma unroll 2
            for (int dd = 0; dd < 64; ++dd) {
                float x = xs[dd * 201 + t];                 // conflict-free (2-way)
                const float* w = W1T + (d0 + dd) * Hdim;    // wave-uniform -> s_load
                #pragma unroll
                for (int h = 0; h < Hdim; ++h) acc[h] = fmaf(x, w[h], acc[h]);
            }
        }
    }

    // ---- logits: att[t] = V . tanh(w1h + w2h) + Vb, masked
    float l = -3e38f;
    if (t < Tdim) {
        float sv = Vb[0];
        #pragma unroll
        for (int h = 0; h < Hdim; ++h) {
            float u = ftanh(acc[h] + w2h_s[h]);
            sv = fmaf(u, Vw[h], sv);
        }
        l = (mask[bs * Tdim + t] == 0) ? NEGV : sv;
    }

    // ---- block softmax over T (4 waves)
    float m = l;
    #pragma unroll
    for (int off = 32; off > 0; off >>= 1) m = fmaxf(m, __shfl_xor(m, off));
    if ((tid & 63) == 0) red[tid >> 6] = m;
    __syncthreads();
    const float M = fmaxf(fmaxf(red[0], red[1]), fmaxf(red[2], red[3]));
    float p = __expf(l - M);            // inactive lanes: exp(-inf) = 0
    float sm = p;
    #pragma unroll
    for (int off = 32; off > 0; off >>= 1) sm += __shfl_xor(sm, off);
    if ((tid & 63) == 0) red[4 + (tid >> 6)] = sm;
    __syncthreads();
    const float Ssum = (red[4] + red[5]) + (red[6] + red[7]);
    if (t < Tdim) att[t] = p / Ssum;
    __syncthreads();

    // ---- pass 2: out[bs][d] = sum_t att[t] * X[t][d]  (coalesced global re-read, L2/L3-hot)
    if (tid < Ddim) {
        const float* xp = Xb + tid;
        float o0 = 0.f, o1 = 0.f, o2 = 0.f, o3 = 0.f;
        for (int tt = 0; tt < Tdim; tt += 4) {
            o0 = fmaf(att[tt],     xp[(tt    ) * Ddim], o0);
            o1 = fmaf(att[tt + 1], xp[(tt + 1) * Ddim], o1);
            o2 = fmaf(att[tt + 2], xp[(tt + 2) * Ddim], o2);
            o3 = fmaf(att[tt + 3], xp[(tt + 3) * Ddim], o3);
        }
        out[bs * Ddim + tid] = (o0 + o1) + (o2 + o3);
    }
}

extern "C" void kernel_launch(void* const* d_in, const int* in_sizes, int n_in,
                              void* d_out, int out_size, void* d_ws, size_t ws_size,
                              hipStream_t stream) {
    const float* X    = (const float*)d_in[0];
    const float* z    = (const float*)d_in[1];
    const int*   mask = (const int*)d_in[2];
    const float* W1   = (const float*)d_in[3];
    const float* W2w  = (const float*)d_in[4];
    const float* W2b  = (const float*)d_in[5];
    const float* Vw   = (const float*)d_in[6];
    const float* Vb   = (const float*)d_in[7];
    float* out = (float*)d_out;

    float* W1T = (float*)d_ws;                    // 8192 floats
    float* w2h = W1T + Hdim * Ddim;               // 3200*64 floats (total ws use ~852 KB)

    transpose_w1<<<32, 256, 0, stream>>>(W1, W1T);
    compute_w2h<<<64, 256, 0, stream>>>(z, W2w, W2b, w2h);
    attn_main<<<NBS, 256, 0, stream>>>(X, mask, Vw, Vb, W1T, w2h, out);
}

// Round 2
// 504.302 us; speedup vs baseline: 1.4026x; 1.4026x over previous
//
#include <hip/hip_runtime.h>

#define Tdim 200
#define Ddim 128
#define Hdim 64
#define NBS  3200
#define NEGV (-1e10f)

typedef __bf16 bf16x8 __attribute__((ext_vector_type(8)));
typedef float  floatx4 __attribute__((ext_vector_type(4)));

__device__ __forceinline__ unsigned short bf16rne(float f) {
    unsigned int u = __float_as_uint(f);
    u += 0x7fffu + ((u >> 16) & 1u);          // round-to-nearest-even (inputs are finite)
    return (unsigned short)(u >> 16);
}

__device__ __forceinline__ float ftanh(float x) {
    // tanh(x) = 1 - 2/(exp(2x)+1); overflow -> rcp(inf)=0 -> 1 (correct tail)
    float e = __expf(2.0f * x);
    return 1.0f - 2.0f * __builtin_amdgcn_rcpf(e + 1.0f);
}

// ---- prep: blocks 0..799 compute w2h (one thread per (bs,h)); blocks 800..803 convert W1 to bf16
__global__ void prep(const float* __restrict__ z, const float* __restrict__ W2w,
                     const float* __restrict__ W2b, const float* __restrict__ W1,
                     unsigned short* __restrict__ W1bf, float* __restrict__ w2h) {
    const int tid = threadIdx.x;
    if (blockIdx.x < 800) {
        const int idx = blockIdx.x * 256 + tid;   // (bs,h); bs wave-uniform -> z via s_load
        const int bs = idx >> 6, h = idx & 63;
        const float* zp = z + bs * 128;
        const float* wp = W2w + h * 128;
        float a = W2b[h];
        #pragma unroll 8
        for (int d = 0; d < 128; ++d) a = fmaf(zp[d], wp[d], a);
        w2h[idx] = a;
    } else {
        const int idx = (blockIdx.x - 800) * 256 + tid;   // 0..1023, 8 floats each
        const float4* src = (const float4*)W1 + idx * 2;
        float4 v0 = src[0], v1 = src[1];
        uint4 o;
        o.x = bf16rne(v0.x) | ((unsigned int)bf16rne(v0.y) << 16);
        o.y = bf16rne(v0.z) | ((unsigned int)bf16rne(v0.w) << 16);
        o.z = bf16rne(v1.x) | ((unsigned int)bf16rne(v1.y) << 16);
        o.w = bf16rne(v1.z) | ((unsigned int)bf16rne(v1.w) << 16);
        ((uint4*)W1bf)[idx] = o;
    }
}

// ---- main: one block (4 waves) per (b,s)
// LDS X layout: bf16, 16B "units"; element (t,k) lives in unit t*16 + ((k>>3) ^ (t&15)),
// byte offset (k&7)*2. XOR swizzle -> conflict-free ds_read_b128 A-frags with NO row padding,
// so total LDS = 53,056 B -> 3 blocks/CU (12 waves).
__global__ __launch_bounds__(256, 3) void attn_main(
    const float* __restrict__ X, const int* __restrict__ mask,
    const float* __restrict__ Vw, const float* __restrict__ Vb,
    const unsigned short* __restrict__ W1bf, const float* __restrict__ w2h_g,
    float* __restrict__ out)
{
    __shared__ __align__(16) unsigned short xs[Tdim * 128];  // 51200 B, swizzled
    __shared__ float attL[Tdim];
    __shared__ float red[8];
    __shared__ float pp[256];

    const int tid = threadIdx.x;
    const int bs  = blockIdx.x;
    const float* __restrict__ Xb = X + (size_t)bs * (Tdim * Ddim);

    // ---- stage X -> bf16 LDS (coalesced float4 reads; 25 iters exactly)
    #pragma unroll 5
    for (int it = 0; it < 25; ++it) {
        int j = it * 256 + tid;
        int t = j >> 5, dq = j & 31;                 // dq: which float4 in the row
        float4 v = *(const float4*)(Xb + t * Ddim + dq * 4);
        unsigned int lo = bf16rne(v.x) | ((unsigned int)bf16rne(v.y) << 16);
        unsigned int hi = bf16rne(v.z) | ((unsigned int)bf16rne(v.w) << 16);
        int u16 = t * 16 + ((dq >> 1) ^ (t & 15));   // physical 16B unit
        *(uint2*)((char*)xs + u16 * 16 + (dq & 1) * 8) = make_uint2(lo, hi);
    }

    const int lane = tid & 63;
    const int wv   = tid >> 6;
    const int l15  = lane & 15, quad = lane >> 4;

    // ---- preload B fragments: B[n][k] = W1[h=n][d=k]; lane holds B[l15+16n][ks*32+quad*8 + j]
    bf16x8 bfrag[4][4];
    #pragma unroll
    for (int n = 0; n < 4; ++n)
        #pragma unroll
        for (int ks = 0; ks < 4; ++ks)
            bfrag[n][ks] = *(const bf16x8*)(W1bf + (n * 16 + l15) * 128 + ks * 32 + quad * 8);

    const float Vb0 = Vb[0];
    float vw[4], w2[4];
    #pragma unroll
    for (int n = 0; n < 4; ++n) {
        int h = l15 + 16 * n;
        vw[n] = Vw[h];
        w2[n] = w2h_g[bs * 64 + h];
    }

    __syncthreads();

    // ---- GEMM1 + logits: wave wv does m-tiles {wv, wv+4, wv+8, wv+12<13}
    // mt=12 clamps t0 to 184 (rows 184..199): overlap with mt=11 recomputes identical
    // values -> benign same-bits double write, and no out-of-range LDS rows.
    for (int mt = wv; mt < 13; mt += 4) {
        const int t0 = (mt == 12) ? 184 : mt * 16;
        const int trow = t0 + l15;                   // A row for this lane
        floatx4 acc[4];
        #pragma unroll
        for (int n = 0; n < 4; ++n) acc[n] = (floatx4){0.f, 0.f, 0.f, 0.f};
        bf16x8 afrag[4];
        #pragma unroll
        for (int ks = 0; ks < 4; ++ks) {
            int u16 = trow * 16 + (((ks << 2) + quad) ^ (trow & 15));
            afrag[ks] = *(const bf16x8*)(xs + u16 * 8);
        }
        #pragma unroll
        for (int n = 0; n < 4; ++n)
            #pragma unroll
            for (int ks = 0; ks < 4; ++ks)
                acc[n] = __builtin_amdgcn_mfma_f32_16x16x32_bf16(afrag[ks], bfrag[n][ks], acc[n], 0, 0, 0);

        // C layout: col(h) = l15 (+16n), row(t) = t0 + quad*4 + r
        float s0 = 0.f, s1 = 0.f, s2 = 0.f, s3 = 0.f;
        #pragma unroll
        for (int n = 0; n < 4; ++n) {
            s0 = fmaf(ftanh(acc[n][0] + w2[n]), vw[n], s0);
            s1 = fmaf(ftanh(acc[n][1] + w2[n]), vw[n], s1);
            s2 = fmaf(ftanh(acc[n][2] + w2[n]), vw[n], s2);
            s3 = fmaf(ftanh(acc[n][3] + w2[n]), vw[n], s3);
        }
        #pragma unroll
        for (int m = 1; m < 16; m <<= 1) {           // reduce over h-lanes (same quad = same rows)
            s0 += __shfl_xor(s0, m);
            s1 += __shfl_xor(s1, m);
            s2 += __shfl_xor(s2, m);
            s3 += __shfl_xor(s3, m);
        }
        if (l15 == 0) {
            const int tb = t0 + quad * 4;
            attL[tb]     = s0 + Vb0;
            attL[tb + 1] = s1 + Vb0;
            attL[tb + 2] = s2 + Vb0;
            attL[tb + 3] = s3 + Vb0;
        }
    }
    __syncthreads();

    // ---- masked softmax over T (4 waves, shuffle + LDS combine)
    float l = -3e38f;
    if (tid < Tdim) {
        l = attL[tid];
        if (mask[bs * Tdim + tid] == 0) l = NEGV;
    }
    float m = l;
    #pragma unroll
    for (int off = 32; off > 0; off >>= 1) m = fmaxf(m, __shfl_xor(m, off));
    if (lane == 0) red[wv] = m;
    __syncthreads();
    const float M = fmaxf(fmaxf(red[0], red[1]), fmaxf(red[2], red[3]));
    float p = __expf(l - M);
    float sm = p;
    #pragma unroll
    for (int off = 32; off > 0; off >>= 1) sm += __shfl_xor(sm, off);
    if (lane == 0) red[4 + wv] = sm;
    __syncthreads();
    const float S = (red[4] + red[5]) + (red[6] + red[7]);
    if (tid < Tdim) attL[tid] = p / S;               // own-slot overwrite, race-free
    __syncthreads();

    // ---- pass 2: out[bs][d] = sum_t att[t] * X[t][d]  (fp32 global re-read, L2/L3-hot)
    const int d = tid & 127, half = tid >> 7;
    const float* xp = Xb + half * 100 * Ddim + d;
    float o = 0.f;
    #pragma unroll 4
    for (int tt = 0; tt < 100; ++tt)
        o = fmaf(attL[half * 100 + tt], xp[tt * Ddim], o);
    pp[tid] = o;
    __syncthreads();
    if (tid < 128) out[bs * Ddim + tid] = pp[tid] + pp[tid + 128];
}

extern "C" void kernel_launch(void* const* d_in, const int* in_sizes, int n_in,
                              void* d_out, int out_size, void* d_ws, size_t ws_size,
                              hipStream_t stream) {
    const float* X    = (const float*)d_in[0];
    const float* z    = (const float*)d_in[1];
    const int*   mask = (const int*)d_in[2];
    const float* W1   = (const float*)d_in[3];
    const float* W2w  = (const float*)d_in[4];
    const float* W2b  = (const float*)d_in[5];
    const float* Vw   = (const float*)d_in[6];
    const float* Vb   = (const float*)d_in[7];
    float* out = (float*)d_out;

    unsigned short* W1bf = (unsigned short*)d_ws;            // 8192 bf16 = 16 KB
    float* w2h = (float*)((char*)d_ws + 16384);              // 3200*64 fp32 = 800 KB

    prep<<<804, 256, 0, stream>>>(z, W2w, W2b, W1, W1bf, w2h);
    attn_main<<<NBS, 256, 0, stream>>>(X, mask, Vw, Vb, W1bf, w2h, out);
}